// Round 7
// baseline (421.001 us; speedup 1.0000x reference)
//
#include <hip/hip_runtime.h>

typedef _Float16 f16;
typedef _Float16 half4 __attribute__((ext_vector_type(4)));
typedef _Float16 half8 __attribute__((ext_vector_type(8)));
typedef float f32x4 __attribute__((ext_vector_type(4)));

#define BATCH 4

// async global -> LDS, 16B per lane; dest = wave-uniform base + lane*16
__device__ __forceinline__ void gload16(const void* g, void* l) {
  __builtin_amdgcn_global_load_lds((const __attribute__((address_space(1))) unsigned int*)g,
                                   (__attribute__((address_space(3))) unsigned int*)l, 16, 0, 0);
}

template<int N> __device__ __forceinline__ void wait_vmcnt() {
  static_assert(N == 0 || N == 8 || N == 10 || N == 12 || N == 16 || N == 20 || N == 24,
                "add literal");
  if constexpr (N == 0)       asm volatile("s_waitcnt vmcnt(0)" ::: "memory");
  else if constexpr (N == 8)  asm volatile("s_waitcnt vmcnt(8)" ::: "memory");
  else if constexpr (N == 10) asm volatile("s_waitcnt vmcnt(10)" ::: "memory");
  else if constexpr (N == 12) asm volatile("s_waitcnt vmcnt(12)" ::: "memory");
  else if constexpr (N == 16) asm volatile("s_waitcnt vmcnt(16)" ::: "memory");
  else if constexpr (N == 20) asm volatile("s_waitcnt vmcnt(20)" ::: "memory");
  else if constexpr (N == 24) asm volatile("s_waitcnt vmcnt(24)" ::: "memory");
}

// ===================== zero the border rows of a padded [DP^3][ROWB] tensor =====================
template<int DP, int ROWB>
__global__ __launch_bounds__(256) void zborder_k(char* __restrict__ buf) {
  int v = blockIdx.x * 256 + threadIdx.x;
  int b = blockIdx.y;
  if (v >= DP * DP * DP) return;
  int w = v % DP; int t = v / DP; int h = t % DP; int d = t / DP;
  bool border = (w == 0) | (w == DP - 1) | (h == 0) | (h == DP - 1) | (d == 0) | (d == DP - 1);
  if (!border) return;
  char* p = buf + ((size_t)b * DP * DP * DP + v) * ROWB;
  #pragma unroll
  for (int i = 0; i < ROWB; i += 8)
    *reinterpret_cast<unsigned long long*>(p + i) = 0ull;
}

// ===================== weight prep =====================
// generic: w[co][ci][27] f32 -> w27[k][co][ci] f16
__global__ __launch_bounds__(256) void wprep_k(const float* __restrict__ w,
                                               f16* __restrict__ w27, int COUT, int CIN) {
  int idx = blockIdx.x * 256 + threadIdx.x;
  int total = COUT * CIN * 27;
  if (idx >= total) return;
  int k = idx % 27;
  int t = idx / 27;
  int ci = t % CIN;
  int co = t / CIN;
  w27[((size_t)k * COUT + co) * CIN + ci] = (f16)w[idx];
}

// conv1: w[64][3][27] f32 -> w1f[co][128] f16, q = k*4 + ci (ci==3 or k>=27 -> 0)
__global__ __launch_bounds__(256) void wprep1_k(const float* __restrict__ w,
                                                f16* __restrict__ wf) {
  int idx = blockIdx.x * 256 + threadIdx.x;   // 64*128
  if (idx >= 64 * 128) return;
  int q = idx & 127, co = idx >> 7;
  int k = q >> 2, ci = q & 3;
  float v = (ci < 3 && k < 27) ? w[(co * 3 + ci) * 27 + k] : 0.f;
  wf[idx] = (f16)v;
}

// xcp[b][pad(v)][4] = mask-active ? x[b][ci][v] : 0 (f16, ch3 = 0); padded 66^3 layout
__global__ __launch_bounds__(256) void xmask_k(const float* __restrict__ x,
                                               const int* __restrict__ mask,
                                               f16* __restrict__ xcp) {
  const int D3 = 262144, PD = 66, PD3 = PD * PD * PD;
  int v = blockIdx.x * 256 + threadIdx.x;
  int b = blockIdx.y;
  bool act = mask[(size_t)b * D3 + v] < 1;
  const float* xb = x + (size_t)b * 3 * D3 + v;
  half4 o;
  o[0] = act ? (f16)xb[0] : (f16)0.f;
  o[1] = act ? (f16)xb[D3] : (f16)0.f;
  o[2] = act ? (f16)xb[2 * D3] : (f16)0.f;
  o[3] = (f16)0.f;
  int ow = v & 63, oh = (v >> 6) & 63, od = v >> 12;
  size_t pv = ((size_t)(od + 1) * PD + oh + 1) * PD + ow + 1;
  *reinterpret_cast<half4*>(xcp + ((size_t)b * PD3 + pv) * 4) = o;
}

// ===================== mask pyramid: separable dilation =====================
__global__ __launch_bounds__(256) void dil_w_k(const int* __restrict__ mask,
                                               unsigned char* __restrict__ aw) {
  const int D3 = 262144;
  int t = blockIdx.x * 256 + threadIdx.x;
  int b = t >> 16;
  int v = (t & 65535) * 4;
  int w0 = v & 63;
  const int* mb = mask + (size_t)b * D3;
  int a[6];
  a[0] = (w0 > 0) ? (mb[v - 1] < 1) : 0;
  #pragma unroll
  for (int i = 0; i < 4; i++) a[i + 1] = mb[v + i] < 1;
  a[5] = (w0 < 60) ? (mb[v + 4] < 1) : 0;
  unsigned int o = 0;
  #pragma unroll
  for (int i = 0; i < 4; i++)
    o |= ((unsigned)(a[i] | a[i + 1] | a[i + 2])) << (8 * i);
  *reinterpret_cast<unsigned int*>(aw + (size_t)b * D3 + v) = o;
}

template<int STRIDE, int DIMSHIFT>
__global__ __launch_bounds__(256) void dil_hd_k(const unsigned char* __restrict__ ai,
                                                unsigned char* __restrict__ ao) {
  const int D3 = 262144;
  int t = blockIdx.x * 256 + threadIdx.x;
  int b = t >> 16;
  int v = (t & 65535) * 4;
  int c = (v >> DIMSHIFT) & 63;
  const unsigned char* ib = ai + (size_t)b * D3;
  unsigned int m = *reinterpret_cast<const unsigned int*>(ib + v);
  if (c > 0)  m |= *reinterpret_cast<const unsigned int*>(ib + v - STRIDE);
  if (c < 63) m |= *reinterpret_cast<const unsigned int*>(ib + v + STRIDE);
  *reinterpret_cast<unsigned int*>(ao + (size_t)b * D3 + v) = m;
}

template<int DIN, int DOUT>
__global__ __launch_bounds__(256) void dilate_s2_k(const unsigned char* __restrict__ mi,
                                                   unsigned char* __restrict__ mo) {
  const int Do3 = DOUT * DOUT * DOUT;
  int v = blockIdx.x * 256 + threadIdx.x;
  if (v >= Do3) return;
  int b = blockIdx.y;
  int ow = v % DOUT, t = v / DOUT, oh = t % DOUT, od = t / DOUT;
  const unsigned char* ib = mi + (size_t)b * DIN * DIN * DIN;
  int act = 0;
  for (int kd = 0; kd < 3; kd++) { int id = od * 2 - 1 + kd; if ((unsigned)id >= (unsigned)DIN) continue;
    for (int kh = 0; kh < 3; kh++) { int ih = oh * 2 - 1 + kh; if ((unsigned)ih >= (unsigned)DIN) continue;
      for (int kw = 0; kw < 3; kw++) { int iw = ow * 2 - 1 + kw; if ((unsigned)iw >= (unsigned)DIN) continue;
        act |= ib[((size_t)id * DIN + ih) * DIN + iw];
      } } }
  mo[(size_t)b * Do3 + v] = (unsigned char)(act ? 1 : 0);
}

// ===================== conv1 via MFMA (padded input, branch-free gather) =====================
template<int BM>
__global__ __launch_bounds__(256) void conv1_mfma_k(const f16* __restrict__ xcp,
                                                    const f16* __restrict__ w1f,
                                                    const float* __restrict__ bias,
                                                    const unsigned char* __restrict__ mo,
                                                    f16* __restrict__ out /* h1p padded */) {
  const int D3 = 262144, COUT = 64, PD = 66, PD3 = PD * PD * PD;
  constexpr int K = 128, LD = K + 8;
  constexpr int WM = 2, WN = 2;
  constexpr int MF = BM / (16 * WM), NF = 64 / (16 * WN);
  __shared__ __align__(16) f16 As[BM][LD];
  __shared__ __align__(16) f16 Bs[64][LD];

  const int tid = threadIdx.x, lane = tid & 63, wave = tid >> 6;
  const int wm = wave >> 1, wn = wave & 1;
  const int v0 = blockIdx.x * BM;
  const int b = blockIdx.y;
  const f16* xb = xcp + (size_t)b * PD3 * 4;

  for (int c = tid; c < 64 * (K / 8); c += 256) {
    int row = c >> 4, cc = c & 15;
    *reinterpret_cast<half8*>(&Bs[row][cc * 8]) =
        *reinterpret_cast<const half8*>(w1f + row * K + cc * 8);
  }
  {
    const int row = tid & (BM - 1);
    const int v = v0 + row;
    const int ow = v & 63, oh = (v >> 6) & 63, od = v >> 12;
    const int base = (od * PD + oh) * PD + ow;
    for (int e = tid; e < 32 * BM; e += 256) {
      int kslot = e / BM;
      half4 val = {};
      if (kslot < 27) {
        int kd = kslot / 9, r2 = kslot - kd * 9, kh = r2 / 3, kw = r2 - kh * 3;
        val = *reinterpret_cast<const half4*>(xb + (size_t)(base + (kd * PD + kh) * PD + kw) * 4);
      }
      *reinterpret_cast<half4*>(&As[row][kslot * 4]) = val;
    }
  }
  __syncthreads();

  f32x4 acc[MF][NF] = {};
  const int chanoff = (lane >> 4) << 3;
  const int arow = wm * MF * 16 + (lane & 15);
  const int brow = wn * NF * 16 + (lane & 15);
  #pragma unroll
  for (int q0 = 0; q0 < K; q0 += 32) {
    half8 a[MF], bb[NF];
    #pragma unroll
    for (int mf = 0; mf < MF; mf++)
      a[mf] = *reinterpret_cast<const half8*>(&As[arow + mf * 16][q0 + chanoff]);
    #pragma unroll
    for (int nf = 0; nf < NF; nf++)
      bb[nf] = *reinterpret_cast<const half8*>(&Bs[brow + nf * 16][q0 + chanoff]);
    #pragma unroll
    for (int mf = 0; mf < MF; mf++)
      #pragma unroll
      for (int nf = 0; nf < NF; nf++)
        acc[mf][nf] = __builtin_amdgcn_mfma_f32_16x16x32_f16(a[mf], bb[nf], acc[mf][nf], 0, 0, 0);
  }

  const unsigned char* mb = mo + (size_t)b * D3;
  f16* ob = out + (size_t)b * PD3 * COUT;
  const int ll = lane & 15, lh = lane >> 4;
  float bv[NF];
  #pragma unroll
  for (int nf = 0; nf < NF; nf++) bv[nf] = bias[wn * NF * 16 + nf * 16 + ll];
  #pragma unroll
  for (int mf = 0; mf < MF; mf++) {
    #pragma unroll
    for (int r = 0; r < 4; r++) {
      int v = v0 + wm * MF * 16 + mf * 16 + (lh << 2) + r;
      bool act = mb[v] != 0;
      int ow = v & 63, oh = (v >> 6) & 63, od = v >> 12;
      size_t pv = ((size_t)(od + 1) * PD + oh + 1) * PD + ow + 1;
      #pragma unroll
      for (int nf = 0; nf < NF; nf++) {
        int co = wn * NF * 16 + nf * 16 + ll;
        float val = acc[mf][nf][r] + bv[nf];
        val = act ? (val > 0.f ? val : 0.f) : 0.f;
        ob[pv * COUT + co] = (f16)val;
      }
    }
  }
}

// ===================== stride-2 conv: N-buffer ring, counted-vmcnt pipeline =====================
// in [B][(DIN+2)^3][CINF] f16 (zero borders), w27 [27][COUT][CINF] f16,
// out OP? [B][(DOUT+2)^3][COUT] : [B][DOUT^3][COUT].
// Per step: wait vmcnt(ahead*L) -> s_barrier -> issue stage(s+D) -> MFMA(buf s%NBUF).
// D = NBUF-1 stages in flight => ~2-3 compute phases of latency cover (T3+T4).
template<int CINS, int CINF, int COUT, int DIN, int DOUT, int BM, int BN,
         int WM, int WN, int NBUF, int SWZ, int OP>
__global__ __launch_bounds__(WM * WN * 64) void conv_mfma3_k(const f16* __restrict__ in,
                                                             const f16* __restrict__ w27,
                                                             const float* __restrict__ bias,
                                                             const unsigned char* __restrict__ mo,
                                                             f16* __restrict__ out) {
  constexpr int PD = DIN + 2, PDo = DOUT + 2;
  constexpr int NW = WM * WN;
  constexpr int MF = BM / (16 * WM), NF = BN / (16 * WN);
  constexpr int ROWB = CINS * 2;          // LDS row bytes (per step)
  constexpr int ROWBF = CINF * 2;         // global row bytes
  constexpr int CHUNKS = ROWB / 16;
  constexpr int RPI = 64 / CHUNKS;        // rows per gload instr
  constexpr int A_IW = BM / RPI / NW;
  constexpr int B_IW = BN / RPI / NW;
  constexpr int L = A_IW + B_IW;          // vm loads per wave per stage
  constexpr int CIH = CINF / CINS;        // 1 or 2 (ci-split)
  constexpr int NSTEP = 27 * CIH;
  constexpr int D = NBUF - 1;             // prefetch depth
  constexpr int D3o = DOUT * DOUT * DOUT;
  constexpr int LOGD = (DOUT == 32) ? 5 : ((DOUT == 16) ? 4 : 3);

  __shared__ __align__(16) char As[NBUF][BM * ROWB];
  __shared__ __align__(16) char Bs[NBUF][BN * ROWB];

  const int tid = threadIdx.x, lane = tid & 63, wave = tid >> 6;
  const int wm = wave / WN, wn = wave % WN;
  int bx = blockIdx.x;
  if (SWZ) {                              // XCD-aware swizzle (gridDim.x % 8 == 0)
    int cpx = gridDim.x >> 3;
    bx = (bx & 7) * cpx + (bx >> 3);
  }
  const int v0 = bx * BM, co0 = blockIdx.y * BN, b = blockIdx.z;
  const char* ib = (const char*)(in + (size_t)b * PD * PD * PD * CINF);

  // ---- per-lane base pointers (computed once; per-step offset is scalar) ----
  const int lrow = lane / CHUNKS;
  const int lchunk = lane % CHUNKS;
  const char* a_src[A_IW];
  #pragma unroll
  for (int i = 0; i < A_IW; i++) {
    int r = (wave * A_IW + i) * RPI + lrow;
    int v = v0 + r;
    int ow = v & (DOUT - 1), oh = (v >> LOGD) & (DOUT - 1), od = v >> (2 * LOGD);
    size_t flat = ((size_t)(2 * od) * PD + 2 * oh) * PD + 2 * ow;
    a_src[i] = ib + flat * ROWBF + (lchunk ^ (r & 7)) * 16;   // pre-swizzled chunk
  }
  const char* b_src[B_IW];
  #pragma unroll
  for (int i = 0; i < B_IW; i++) {
    int r = (wave * B_IW + i) * RPI + lrow;
    b_src[i] = (const char*)w27 + (size_t)(co0 + r) * ROWBF + (lchunk ^ (r & 7)) * 16;
  }

  auto stage = [&](int buf, int s) {
    int k = (CIH == 2) ? (s >> 1) : s;
    int h = (CIH == 2) ? (s & 1) : 0;
    int kd = k / 9, r2 = k - kd * 9, kh = r2 / 3, kw = r2 - kh * 3;
    int koff = ((kd * PD + kh) * PD + kw) * ROWBF + h * ROWB;   // scalar per step
    #pragma unroll
    for (int i = 0; i < A_IW; i++)
      gload16(a_src[i] + koff, &As[buf][(wave * A_IW + i) * 1024]);
    size_t wko = (size_t)k * COUT * ROWBF + h * ROWB;
    #pragma unroll
    for (int i = 0; i < B_IW; i++)
      gload16(b_src[i] + wko, &Bs[buf][(wave * B_IW + i) * 1024]);
  };

  f32x4 acc[MF][NF] = {};
  const int ll = lane & 15, lh = lane >> 4;
  const int ra0 = wm * MF * 16 + ll;
  const int rb0 = wn * NF * 16 + ll;
  const int rswa = ra0 & 7;               // (row + mf*16) & 7 == row & 7
  const int rswb = rb0 & 7;

  #pragma unroll
  for (int i = 0; i < D; i++) stage(i, i);

  int cur = 0;
  for (int s = 0; s < NSTEP; s++) {
    int ahead = NSTEP - 1 - s;            // stages allowed to stay in flight
    if (ahead > D - 1) ahead = D - 1;
    if (ahead >= 2)      wait_vmcnt<2 * L>();
    else if (ahead == 1) wait_vmcnt<L>();
    else                 wait_vmcnt<0>();
    __builtin_amdgcn_s_barrier();
    asm volatile("" ::: "memory");
    if (s + D < NSTEP) {
      int sb = cur - 1; if (sb < 0) sb += NBUF;   // (s+D) % NBUF
      stage(sb, s + D);
    }
    #pragma unroll
    for (int ci0 = 0; ci0 < CINS; ci0 += 32) {
      const int q = (ci0 >> 3) + lh;
      half8 a[MF], bb[NF];
      #pragma unroll
      for (int mf = 0; mf < MF; mf++)
        a[mf] = *reinterpret_cast<const half8*>(
            &As[cur][(ra0 + mf * 16) * ROWB + ((q ^ rswa) * 16)]);
      #pragma unroll
      for (int nf = 0; nf < NF; nf++)
        bb[nf] = *reinterpret_cast<const half8*>(
            &Bs[cur][(rb0 + nf * 16) * ROWB + ((q ^ rswb) * 16)]);
      #pragma unroll
      for (int mf = 0; mf < MF; mf++)
        #pragma unroll
        for (int nf = 0; nf < NF; nf++)
          acc[mf][nf] = __builtin_amdgcn_mfma_f32_16x16x32_f16(a[mf], bb[nf], acc[mf][nf], 0, 0, 0);
    }
    asm volatile("" ::: "memory");
    cur = (cur + 1 == NBUF) ? 0 : cur + 1;
  }

  // ---- epilogue ----
  const unsigned char* mb = mo + (size_t)b * D3o;
  f16* ob = out + (size_t)b * (OP ? PDo * PDo * PDo : D3o) * COUT;
  float bv[NF];
  #pragma unroll
  for (int nf = 0; nf < NF; nf++) bv[nf] = bias[co0 + wn * NF * 16 + nf * 16 + ll];
  #pragma unroll
  for (int mf = 0; mf < MF; mf++) {
    #pragma unroll
    for (int r = 0; r < 4; r++) {
      int v = v0 + wm * MF * 16 + mf * 16 + (lh << 2) + r;
      bool act = mb[v] != 0;
      int ow = v & (DOUT - 1), oh = (v >> LOGD) & (DOUT - 1), od = v >> (2 * LOGD);
      size_t pv = OP ? (((size_t)(od + 1) * PDo + oh + 1) * PDo + ow + 1) : (size_t)v;
      #pragma unroll
      for (int nf = 0; nf < NF; nf++) {
        int co = co0 + wn * NF * 16 + nf * 16 + ll;
        float val = acc[mf][nf][r] + bv[nf];
        val = act ? (val > 0.f ? val : 0.f) : 0.f;
        ob[pv * COUT + co] = (f16)val;
      }
    }
  }
}

// ===================== max pool + leaky relu =====================
__global__ __launch_bounds__(256) void pool_k(const f16* __restrict__ h4,
                                              float* __restrict__ outp) {
  __shared__ float red[4][64];
  int b = blockIdx.y;
  int cl = threadIdx.x & 63;
  int co = blockIdx.x * 64 + cl;
  int vg = threadIdx.x >> 6;
  const f16* p = h4 + (size_t)b * 512 * 512;
  float m = 0.f;
  for (int v = vg * 128; v < vg * 128 + 128; v++) m = fmaxf(m, (float)p[(size_t)v * 512 + co]);
  red[vg][cl] = m;
  __syncthreads();
  if (threadIdx.x < 64) {
    m = fmaxf(fmaxf(red[0][threadIdx.x], red[1][threadIdx.x]),
              fmaxf(red[2][threadIdx.x], red[3][threadIdx.x]));
    float r = (m >= 0.f) ? m : 0.2f * m;
    outp[b * 512 + blockIdx.x * 64 + threadIdx.x] = r;
  }
}

extern "C" void kernel_launch(void* const* d_in, const int* in_sizes, int n_in,
                              void* d_out, int out_size, void* d_ws, size_t ws_size,
                              hipStream_t stream) {
  const float* x    = (const float*)d_in[0];
  const int*   mask = (const int*)d_in[1];
  const float* w1 = (const float*)d_in[2];
  const float* b1 = (const float*)d_in[3];
  const float* w2 = (const float*)d_in[4];
  const float* b2 = (const float*)d_in[5];
  const float* w3 = (const float*)d_in[6];
  const float* b3 = (const float*)d_in[7];
  const float* w4 = (const float*)d_in[8];
  const float* b4 = (const float*)d_in[9];
  float* outp = (float*)d_out;

  const size_t PD1 = 66 * 66 * 66;   // 287496
  const size_t PD2 = 34 * 34 * 34;   // 39304
  const size_t PD3s = 18 * 18 * 18;  // 5832

  char* ws = (char*)d_ws;
  size_t off = 0;
  auto alloc = [&](size_t bytes) -> char* {
    char* p = ws + off;
    off = (off + bytes + 255) & ~(size_t)255;
    return p;
  };
  f16* wf1 = (f16*)alloc((size_t)64 * 128 * 2);
  f16* wf2 = (f16*)alloc((size_t)27 * 128 * 64 * 2);
  f16* wf3 = (f16*)alloc((size_t)27 * 256 * 128 * 2);
  f16* wf4 = (f16*)alloc((size_t)27 * 512 * 256 * 2);
  unsigned char* aw = (unsigned char*)alloc((size_t)BATCH * 262144);
  unsigned char* ah = (unsigned char*)alloc((size_t)BATCH * 262144);
  unsigned char* m1 = (unsigned char*)alloc((size_t)BATCH * 262144);
  unsigned char* m2 = (unsigned char*)alloc((size_t)BATCH * 32768);
  unsigned char* m3 = (unsigned char*)alloc((size_t)BATCH * 4096);
  unsigned char* m4 = (unsigned char*)alloc((size_t)BATCH * 512);
  f16* h1p = (f16*)alloc((size_t)BATCH * PD1 * 64 * 2);    // 147 MB
  f16* h2p = (f16*)alloc((size_t)BATCH * PD2 * 128 * 2);   // 40 MB
  f16* h3p = (f16*)alloc((size_t)BATCH * PD3s * 256 * 2);  // 12 MB
  f16* h4  = (f16*)alloc((size_t)BATCH * 512 * 512 * 2);   // 2 MB
  // xcp (B*66^3*4 f16 = 9.2 MB) aliases h3p (12 MB): xcp dead after conv1,
  // h3p border-zero runs after conv1, before conv3.
  f16* xcp = h3p;
  if (off > ws_size) return;

  // prep
  wprep1_k<<<dim3((64 * 128 + 255) / 256), 256, 0, stream>>>(w1, wf1);
  wprep_k<<<dim3((128 * 64 * 27 + 255) / 256), 256, 0, stream>>>(w2, wf2, 128, 64);
  wprep_k<<<dim3((256 * 128 * 27 + 255) / 256), 256, 0, stream>>>(w3, wf3, 256, 128);
  wprep_k<<<dim3((512 * 256 * 27 + 255) / 256), 256, 0, stream>>>(w4, wf4, 512, 256);

  // mask pyramid
  dil_w_k<<<dim3(BATCH * 65536 / 256), 256, 0, stream>>>(mask, aw);
  dil_hd_k<64, 6><<<dim3(BATCH * 65536 / 256), 256, 0, stream>>>(aw, ah);
  dil_hd_k<4096, 12><<<dim3(BATCH * 65536 / 256), 256, 0, stream>>>(ah, m1);
  dilate_s2_k<64, 32><<<dim3(128, BATCH), 256, 0, stream>>>(m1, m2);
  dilate_s2_k<32, 16><<<dim3(16, BATCH), 256, 0, stream>>>(m2, m3);
  dilate_s2_k<16, 8><<<dim3(2, BATCH), 256, 0, stream>>>(m3, m4);

  // padded-input prep: interior writes + border zeroing
  xmask_k<<<dim3(1024, BATCH), 256, 0, stream>>>(x, mask, xcp);
  zborder_k<66, 8><<<dim3((287496 + 255) / 256, BATCH), 256, 0, stream>>>((char*)xcp);
  zborder_k<66, 128><<<dim3((287496 + 255) / 256, BATCH), 256, 0, stream>>>((char*)h1p);
  zborder_k<34, 256><<<dim3((39304 + 255) / 256, BATCH), 256, 0, stream>>>((char*)h2p);

  // conv1 (reads xcp, writes h1p interior)
  conv1_mfma_k<128><<<dim3(262144 / 128, BATCH), 256, 0, stream>>>(xcp, wf1, b1, m1, h1p);

  // h3p border-zero AFTER conv1 (h3p aliases xcp)
  zborder_k<18, 512><<<dim3((5832 + 255) / 256, BATCH), 256, 0, stream>>>((char*)h3p);

  // conv blocks: N-buffer counted-vmcnt pipeline
  // conv2: CIN64 COUT128, BM128 BN128, 4 waves MF4xNF4, NBUF=4 (128KB LDS), L=8
  conv_mfma3_k<64, 64, 128, 64, 32, 128, 128, 2, 2, 4, 1, 1>
      <<<dim3(256, 1, BATCH), 256, 0, stream>>>(h1p, wf2, b2, m2, h2p);
  // conv3: CIN128 COUT256, BM64 BN128, 4 waves MF2xNF4, NBUF=3 (144KB LDS), L=12
  conv_mfma3_k<128, 128, 256, 32, 16, 64, 128, 2, 2, 3, 0, 1>
      <<<dim3(64, 2, BATCH), 256, 0, stream>>>(h2p, wf3, b3, m3, h3p);
  // conv4: CIN256 (ci-split 2x128) COUT512, BM32 BN128, 4 waves MF2xNF2, NBUF=3 (120KB), L=10
  conv_mfma3_k<128, 256, 512, 16, 8, 32, 128, 1, 4, 3, 0, 0>
      <<<dim3(16, 4, BATCH), 256, 0, stream>>>(h3p, wf4, b4, m4, h4);

  // pool + leaky relu
  pool_k<<<dim3(8, BATCH), 256, 0, stream>>>(h4, outp);
}

// Round 8
// 351.838 us; speedup vs baseline: 1.1966x; 1.1966x over previous
//
#include <hip/hip_runtime.h>

typedef _Float16 f16;
typedef _Float16 half4 __attribute__((ext_vector_type(4)));
typedef _Float16 half8 __attribute__((ext_vector_type(8)));
typedef float f32x4 __attribute__((ext_vector_type(4)));

#define BATCH 4

// async global -> LDS, 16B per lane; dest = wave-uniform base + lane*16
__device__ __forceinline__ void gload16(const void* g, void* l) {
  __builtin_amdgcn_global_load_lds((const __attribute__((address_space(1))) unsigned int*)g,
                                   (__attribute__((address_space(3))) unsigned int*)l, 16, 0, 0);
}

// ===================== zero the border rows of a padded [DP^3][ROWB] tensor =====================
template<int DP, int ROWB>
__global__ __launch_bounds__(256) void zborder_k(char* __restrict__ buf) {
  int v = blockIdx.x * 256 + threadIdx.x;
  int b = blockIdx.y;
  if (v >= DP * DP * DP) return;
  int w = v % DP; int t = v / DP; int h = t % DP; int d = t / DP;
  bool border = (w == 0) | (w == DP - 1) | (h == 0) | (h == DP - 1) | (d == 0) | (d == DP - 1);
  if (!border) return;
  char* p = buf + ((size_t)b * DP * DP * DP + v) * ROWB;
  #pragma unroll
  for (int i = 0; i < ROWB; i += 8)
    *reinterpret_cast<unsigned long long*>(p + i) = 0ull;
}

// ===================== weight prep =====================
// generic: w[co][ci][27] f32 -> w27[k][co][ci] f16
__global__ __launch_bounds__(256) void wprep_k(const float* __restrict__ w,
                                               f16* __restrict__ w27, int COUT, int CIN) {
  int idx = blockIdx.x * 256 + threadIdx.x;
  int total = COUT * CIN * 27;
  if (idx >= total) return;
  int k = idx % 27;
  int t = idx / 27;
  int ci = t % CIN;
  int co = t / CIN;
  w27[((size_t)k * COUT + co) * CIN + ci] = (f16)w[idx];
}

// conv1: w[64][3][27] f32 -> w1f[co][128] f16, q = k*4 + ci (ci==3 or k>=27 -> 0)
__global__ __launch_bounds__(256) void wprep1_k(const float* __restrict__ w,
                                                f16* __restrict__ wf) {
  int idx = blockIdx.x * 256 + threadIdx.x;   // 64*128
  if (idx >= 64 * 128) return;
  int q = idx & 127, co = idx >> 7;
  int k = q >> 2, ci = q & 3;
  float v = (ci < 3 && k < 27) ? w[(co * 3 + ci) * 27 + k] : 0.f;
  wf[idx] = (f16)v;
}

// xcp[b][pad(v)][4] = mask-active ? x[b][ci][v] : 0 (f16, ch3 = 0); padded 66^3 layout
__global__ __launch_bounds__(256) void xmask_k(const float* __restrict__ x,
                                               const int* __restrict__ mask,
                                               f16* __restrict__ xcp) {
  const int D3 = 262144, PD = 66, PD3 = PD * PD * PD;
  int v = blockIdx.x * 256 + threadIdx.x;
  int b = blockIdx.y;
  bool act = mask[(size_t)b * D3 + v] < 1;
  const float* xb = x + (size_t)b * 3 * D3 + v;
  half4 o;
  o[0] = act ? (f16)xb[0] : (f16)0.f;
  o[1] = act ? (f16)xb[D3] : (f16)0.f;
  o[2] = act ? (f16)xb[2 * D3] : (f16)0.f;
  o[3] = (f16)0.f;
  int ow = v & 63, oh = (v >> 6) & 63, od = v >> 12;
  size_t pv = ((size_t)(od + 1) * PD + oh + 1) * PD + ow + 1;
  *reinterpret_cast<half4*>(xcp + ((size_t)b * PD3 + pv) * 4) = o;
}

// ===================== mask pyramid: separable dilation =====================
__global__ __launch_bounds__(256) void dil_w_k(const int* __restrict__ mask,
                                               unsigned char* __restrict__ aw) {
  const int D3 = 262144;
  int t = blockIdx.x * 256 + threadIdx.x;
  int b = t >> 16;
  int v = (t & 65535) * 4;
  int w0 = v & 63;
  const int* mb = mask + (size_t)b * D3;
  int a[6];
  a[0] = (w0 > 0) ? (mb[v - 1] < 1) : 0;
  #pragma unroll
  for (int i = 0; i < 4; i++) a[i + 1] = mb[v + i] < 1;
  a[5] = (w0 < 60) ? (mb[v + 4] < 1) : 0;
  unsigned int o = 0;
  #pragma unroll
  for (int i = 0; i < 4; i++)
    o |= ((unsigned)(a[i] | a[i + 1] | a[i + 2])) << (8 * i);
  *reinterpret_cast<unsigned int*>(aw + (size_t)b * D3 + v) = o;
}

template<int STRIDE, int DIMSHIFT>
__global__ __launch_bounds__(256) void dil_hd_k(const unsigned char* __restrict__ ai,
                                                unsigned char* __restrict__ ao) {
  const int D3 = 262144;
  int t = blockIdx.x * 256 + threadIdx.x;
  int b = t >> 16;
  int v = (t & 65535) * 4;
  int c = (v >> DIMSHIFT) & 63;
  const unsigned char* ib = ai + (size_t)b * D3;
  unsigned int m = *reinterpret_cast<const unsigned int*>(ib + v);
  if (c > 0)  m |= *reinterpret_cast<const unsigned int*>(ib + v - STRIDE);
  if (c < 63) m |= *reinterpret_cast<const unsigned int*>(ib + v + STRIDE);
  *reinterpret_cast<unsigned int*>(ao + (size_t)b * D3 + v) = m;
}

template<int DIN, int DOUT>
__global__ __launch_bounds__(256) void dilate_s2_k(const unsigned char* __restrict__ mi,
                                                   unsigned char* __restrict__ mo) {
  const int Do3 = DOUT * DOUT * DOUT;
  int v = blockIdx.x * 256 + threadIdx.x;
  if (v >= Do3) return;
  int b = blockIdx.y;
  int ow = v % DOUT, t = v / DOUT, oh = t % DOUT, od = t / DOUT;
  const unsigned char* ib = mi + (size_t)b * DIN * DIN * DIN;
  int act = 0;
  for (int kd = 0; kd < 3; kd++) { int id = od * 2 - 1 + kd; if ((unsigned)id >= (unsigned)DIN) continue;
    for (int kh = 0; kh < 3; kh++) { int ih = oh * 2 - 1 + kh; if ((unsigned)ih >= (unsigned)DIN) continue;
      for (int kw = 0; kw < 3; kw++) { int iw = ow * 2 - 1 + kw; if ((unsigned)iw >= (unsigned)DIN) continue;
        act |= ib[((size_t)id * DIN + ih) * DIN + iw];
      } } }
  mo[(size_t)b * Do3 + v] = (unsigned char)(act ? 1 : 0);
}

// ===================== conv1 via MFMA (padded input, branch-free gather) =====================
template<int BM>
__global__ __launch_bounds__(256) void conv1_mfma_k(const f16* __restrict__ xcp,
                                                    const f16* __restrict__ w1f,
                                                    const float* __restrict__ bias,
                                                    const unsigned char* __restrict__ mo,
                                                    f16* __restrict__ out /* h1p padded */) {
  const int D3 = 262144, COUT = 64, PD = 66, PD3 = PD * PD * PD;
  constexpr int K = 128, LD = K + 8;
  constexpr int WM = 2, WN = 2;
  constexpr int MF = BM / (16 * WM), NF = 64 / (16 * WN);
  __shared__ __align__(16) f16 As[BM][LD];
  __shared__ __align__(16) f16 Bs[64][LD];

  const int tid = threadIdx.x, lane = tid & 63, wave = tid >> 6;
  const int wm = wave >> 1, wn = wave & 1;
  const int v0 = blockIdx.x * BM;
  const int b = blockIdx.y;
  const f16* xb = xcp + (size_t)b * PD3 * 4;

  for (int c = tid; c < 64 * (K / 8); c += 256) {
    int row = c >> 4, cc = c & 15;
    *reinterpret_cast<half8*>(&Bs[row][cc * 8]) =
        *reinterpret_cast<const half8*>(w1f + row * K + cc * 8);
  }
  {
    const int row = tid & (BM - 1);
    const int v = v0 + row;
    const int ow = v & 63, oh = (v >> 6) & 63, od = v >> 12;
    const int base = (od * PD + oh) * PD + ow;
    for (int e = tid; e < 32 * BM; e += 256) {
      int kslot = e / BM;
      half4 val = {};
      if (kslot < 27) {
        int kd = kslot / 9, r2 = kslot - kd * 9, kh = r2 / 3, kw = r2 - kh * 3;
        val = *reinterpret_cast<const half4*>(xb + (size_t)(base + (kd * PD + kh) * PD + kw) * 4);
      }
      *reinterpret_cast<half4*>(&As[row][kslot * 4]) = val;
    }
  }
  __syncthreads();

  f32x4 acc[MF][NF] = {};
  const int chanoff = (lane >> 4) << 3;
  const int arow = wm * MF * 16 + (lane & 15);
  const int brow = wn * NF * 16 + (lane & 15);
  #pragma unroll
  for (int q0 = 0; q0 < K; q0 += 32) {
    half8 a[MF], bb[NF];
    #pragma unroll
    for (int mf = 0; mf < MF; mf++)
      a[mf] = *reinterpret_cast<const half8*>(&As[arow + mf * 16][q0 + chanoff]);
    #pragma unroll
    for (int nf = 0; nf < NF; nf++)
      bb[nf] = *reinterpret_cast<const half8*>(&Bs[brow + nf * 16][q0 + chanoff]);
    #pragma unroll
    for (int mf = 0; mf < MF; mf++)
      #pragma unroll
      for (int nf = 0; nf < NF; nf++)
        acc[mf][nf] = __builtin_amdgcn_mfma_f32_16x16x32_f16(a[mf], bb[nf], acc[mf][nf], 0, 0, 0);
  }

  const unsigned char* mb = mo + (size_t)b * D3;
  f16* ob = out + (size_t)b * PD3 * COUT;
  const int ll = lane & 15, lh = lane >> 4;
  float bv[NF];
  #pragma unroll
  for (int nf = 0; nf < NF; nf++) bv[nf] = bias[wn * NF * 16 + nf * 16 + ll];
  #pragma unroll
  for (int mf = 0; mf < MF; mf++) {
    #pragma unroll
    for (int r = 0; r < 4; r++) {
      int v = v0 + wm * MF * 16 + mf * 16 + (lh << 2) + r;
      bool act = mb[v] != 0;
      int ow = v & 63, oh = (v >> 6) & 63, od = v >> 12;
      size_t pv = ((size_t)(od + 1) * PD + oh + 1) * PD + ow + 1;
      #pragma unroll
      for (int nf = 0; nf < NF; nf++) {
        int co = wn * NF * 16 + nf * 16 + ll;
        float val = acc[mf][nf][r] + bv[nf];
        val = act ? (val > 0.f ? val : 0.f) : 0.f;
        ob[pv * COUT + co] = (f16)val;
      }
    }
  }
}

// ===================== stride-2 conv, 2-phase pipelined MFMA, padded I/O, ci-split =====================
// in [B][(DIN+2)^3][CINF] f16 (zero borders), w27 [27][COUT][CINF] f16,
// out OP? [B][(DOUT+2)^3][COUT] : [B][DOUT^3][COUT].
// 2-phase: prefetch step s+1 before computing step s; __syncthreads drains vmcnt.
// Occupancy-first tiles: LDS <= 48-64KB -> 2-3 blocks/CU (cross-block TLP hides HBM).
template<int CINS, int CINF, int COUT, int DIN, int DOUT, int BM, int BN,
         int WM, int WN, int SWZ, int OP>
__global__ __launch_bounds__(WM * WN * 64) void conv_mfma2_k(const f16* __restrict__ in,
                                                             const f16* __restrict__ w27,
                                                             const float* __restrict__ bias,
                                                             const unsigned char* __restrict__ mo,
                                                             f16* __restrict__ out) {
  constexpr int PD = DIN + 2, PDo = DOUT + 2;
  constexpr int NW = WM * WN;
  constexpr int MF = BM / (16 * WM), NF = BN / (16 * WN);
  constexpr int ROWB = CINS * 2;          // LDS row bytes (per step)
  constexpr int ROWBF = CINF * 2;         // global row bytes
  constexpr int CHUNKS = ROWB / 16;
  constexpr int RPI = 64 / CHUNKS;        // rows per gload instr
  constexpr int A_IW = BM / RPI / NW;
  constexpr int B_IW = BN / RPI / NW;
  constexpr int CIH = CINF / CINS;        // 1 or 2 (ci-split)
  constexpr int NSTEP = 27 * CIH;
  constexpr int D3o = DOUT * DOUT * DOUT;
  constexpr int LOGD = (DOUT == 32) ? 5 : ((DOUT == 16) ? 4 : 3);

  __shared__ __align__(16) char As[2][BM * ROWB];
  __shared__ __align__(16) char Bs[2][BN * ROWB];

  const int tid = threadIdx.x, lane = tid & 63, wave = tid >> 6;
  const int wm = wave / WN, wn = wave % WN;
  int bx = blockIdx.x;
  if (SWZ) {                              // XCD-aware swizzle (gridDim.x % 8 == 0)
    int cpx = gridDim.x >> 3;
    bx = (bx & 7) * cpx + (bx >> 3);
  }
  const int v0 = bx * BM, co0 = blockIdx.y * BN, b = blockIdx.z;
  const char* ib = (const char*)(in + (size_t)b * PD * PD * PD * CINF);

  // ---- per-lane base pointers (computed once; per-step offset is scalar) ----
  const int lrow = lane / CHUNKS;
  const int lchunk = lane % CHUNKS;
  const char* a_src[A_IW];
  #pragma unroll
  for (int i = 0; i < A_IW; i++) {
    int r = (wave * A_IW + i) * RPI + lrow;
    int v = v0 + r;
    int ow = v & (DOUT - 1), oh = (v >> LOGD) & (DOUT - 1), od = v >> (2 * LOGD);
    size_t flat = ((size_t)(2 * od) * PD + 2 * oh) * PD + 2 * ow;
    a_src[i] = ib + flat * ROWBF + (lchunk ^ (r & 7)) * 16;   // pre-swizzled chunk
  }
  const char* b_src[B_IW];
  #pragma unroll
  for (int i = 0; i < B_IW; i++) {
    int r = (wave * B_IW + i) * RPI + lrow;
    b_src[i] = (const char*)w27 + (size_t)(co0 + r) * ROWBF + (lchunk ^ (r & 7)) * 16;
  }

  auto stage = [&](int buf, int s) {
    int k = (CIH == 2) ? (s >> 1) : s;
    int h = (CIH == 2) ? (s & 1) : 0;
    int kd = k / 9, r2 = k - kd * 9, kh = r2 / 3, kw = r2 - kh * 3;
    int koff = ((kd * PD + kh) * PD + kw) * ROWBF + h * ROWB;   // scalar per step
    #pragma unroll
    for (int i = 0; i < A_IW; i++)
      gload16(a_src[i] + koff, &As[buf][(wave * A_IW + i) * 1024]);
    size_t wko = (size_t)k * COUT * ROWBF + h * ROWB;
    #pragma unroll
    for (int i = 0; i < B_IW; i++)
      gload16(b_src[i] + wko, &Bs[buf][(wave * B_IW + i) * 1024]);
  };

  f32x4 acc[MF][NF] = {};
  const int ll = lane & 15, lh = lane >> 4;
  const int ra0 = wm * MF * 16 + ll;
  const int rb0 = wn * NF * 16 + ll;
  const int rswa = ra0 & 7;               // (row + mf*16) & 7 == row & 7
  const int rswb = rb0 & 7;

  stage(0, 0);
  __syncthreads();                        // drains vmcnt(0)
  int cur = 0;
  for (int s = 0; s < NSTEP; s++) {
    if (s < NSTEP - 1) stage(cur ^ 1, s + 1);   // prefetch overlaps this step's MFMA
    #pragma unroll
    for (int ci0 = 0; ci0 < CINS; ci0 += 32) {
      const int q = (ci0 >> 3) + lh;
      half8 a[MF], bb[NF];
      #pragma unroll
      for (int mf = 0; mf < MF; mf++)
        a[mf] = *reinterpret_cast<const half8*>(
            &As[cur][(ra0 + mf * 16) * ROWB + ((q ^ rswa) * 16)]);
      #pragma unroll
      for (int nf = 0; nf < NF; nf++)
        bb[nf] = *reinterpret_cast<const half8*>(
            &Bs[cur][(rb0 + nf * 16) * ROWB + ((q ^ rswb) * 16)]);
      #pragma unroll
      for (int mf = 0; mf < MF; mf++)
        #pragma unroll
        for (int nf = 0; nf < NF; nf++)
          acc[mf][nf] = __builtin_amdgcn_mfma_f32_16x16x32_f16(a[mf], bb[nf], acc[mf][nf], 0, 0, 0);
    }
    __syncthreads();                      // drains prefetch vmcnt + syncs LDS reads
    cur ^= 1;
  }

  // ---- epilogue ----
  const unsigned char* mb = mo + (size_t)b * D3o;
  f16* ob = out + (size_t)b * (OP ? PDo * PDo * PDo : D3o) * COUT;
  float bv[NF];
  #pragma unroll
  for (int nf = 0; nf < NF; nf++) bv[nf] = bias[co0 + wn * NF * 16 + nf * 16 + ll];
  #pragma unroll
  for (int mf = 0; mf < MF; mf++) {
    #pragma unroll
    for (int r = 0; r < 4; r++) {
      int v = v0 + wm * MF * 16 + mf * 16 + (lh << 2) + r;
      bool act = mb[v] != 0;
      int ow = v & (DOUT - 1), oh = (v >> LOGD) & (DOUT - 1), od = v >> (2 * LOGD);
      size_t pv = OP ? (((size_t)(od + 1) * PDo + oh + 1) * PDo + ow + 1) : (size_t)v;
      #pragma unroll
      for (int nf = 0; nf < NF; nf++) {
        int co = co0 + wn * NF * 16 + nf * 16 + ll;
        float val = acc[mf][nf][r] + bv[nf];
        val = act ? (val > 0.f ? val : 0.f) : 0.f;
        ob[pv * COUT + co] = (f16)val;
      }
    }
  }
}

// ===================== max pool + leaky relu =====================
__global__ __launch_bounds__(256) void pool_k(const f16* __restrict__ h4,
                                              float* __restrict__ outp) {
  __shared__ float red[4][64];
  int b = blockIdx.y;
  int cl = threadIdx.x & 63;
  int co = blockIdx.x * 64 + cl;
  int vg = threadIdx.x >> 6;
  const f16* p = h4 + (size_t)b * 512 * 512;
  float m = 0.f;
  for (int v = vg * 128; v < vg * 128 + 128; v++) m = fmaxf(m, (float)p[(size_t)v * 512 + co]);
  red[vg][cl] = m;
  __syncthreads();
  if (threadIdx.x < 64) {
    m = fmaxf(fmaxf(red[0][threadIdx.x], red[1][threadIdx.x]),
              fmaxf(red[2][threadIdx.x], red[3][threadIdx.x]));
    float r = (m >= 0.f) ? m : 0.2f * m;
    outp[b * 512 + blockIdx.x * 64 + threadIdx.x] = r;
  }
}

extern "C" void kernel_launch(void* const* d_in, const int* in_sizes, int n_in,
                              void* d_out, int out_size, void* d_ws, size_t ws_size,
                              hipStream_t stream) {
  const float* x    = (const float*)d_in[0];
  const int*   mask = (const int*)d_in[1];
  const float* w1 = (const float*)d_in[2];
  const float* b1 = (const float*)d_in[3];
  const float* w2 = (const float*)d_in[4];
  const float* b2 = (const float*)d_in[5];
  const float* w3 = (const float*)d_in[6];
  const float* b3 = (const float*)d_in[7];
  const float* w4 = (const float*)d_in[8];
  const float* b4 = (const float*)d_in[9];
  float* outp = (float*)d_out;

  const size_t PD1 = 66 * 66 * 66;   // 287496
  const size_t PD2 = 34 * 34 * 34;   // 39304
  const size_t PD3s = 18 * 18 * 18;  // 5832

  char* ws = (char*)d_ws;
  size_t off = 0;
  auto alloc = [&](size_t bytes) -> char* {
    char* p = ws + off;
    off = (off + bytes + 255) & ~(size_t)255;
    return p;
  };
  f16* wf1 = (f16*)alloc((size_t)64 * 128 * 2);
  f16* wf2 = (f16*)alloc((size_t)27 * 128 * 64 * 2);
  f16* wf3 = (f16*)alloc((size_t)27 * 256 * 128 * 2);
  f16* wf4 = (f16*)alloc((size_t)27 * 512 * 256 * 2);
  unsigned char* aw = (unsigned char*)alloc((size_t)BATCH * 262144);
  unsigned char* ah = (unsigned char*)alloc((size_t)BATCH * 262144);
  unsigned char* m1 = (unsigned char*)alloc((size_t)BATCH * 262144);
  unsigned char* m2 = (unsigned char*)alloc((size_t)BATCH * 32768);
  unsigned char* m3 = (unsigned char*)alloc((size_t)BATCH * 4096);
  unsigned char* m4 = (unsigned char*)alloc((size_t)BATCH * 512);
  f16* h1p = (f16*)alloc((size_t)BATCH * PD1 * 64 * 2);    // 147 MB
  f16* h2p = (f16*)alloc((size_t)BATCH * PD2 * 128 * 2);   // 40 MB
  f16* h3p = (f16*)alloc((size_t)BATCH * PD3s * 256 * 2);  // 12 MB
  f16* h4  = (f16*)alloc((size_t)BATCH * 512 * 512 * 2);   // 2 MB
  // xcp (B*66^3*4 f16 = 9.2 MB) aliases h3p (12 MB): xcp dead after conv1,
  // h3p border-zero runs after conv1, before conv3.
  f16* xcp = h3p;
  if (off > ws_size) return;

  // prep
  wprep1_k<<<dim3((64 * 128 + 255) / 256), 256, 0, stream>>>(w1, wf1);
  wprep_k<<<dim3((128 * 64 * 27 + 255) / 256), 256, 0, stream>>>(w2, wf2, 128, 64);
  wprep_k<<<dim3((256 * 128 * 27 + 255) / 256), 256, 0, stream>>>(w3, wf3, 256, 128);
  wprep_k<<<dim3((512 * 256 * 27 + 255) / 256), 256, 0, stream>>>(w4, wf4, 512, 256);

  // mask pyramid
  dil_w_k<<<dim3(BATCH * 65536 / 256), 256, 0, stream>>>(mask, aw);
  dil_hd_k<64, 6><<<dim3(BATCH * 65536 / 256), 256, 0, stream>>>(aw, ah);
  dil_hd_k<4096, 12><<<dim3(BATCH * 65536 / 256), 256, 0, stream>>>(ah, m1);
  dilate_s2_k<64, 32><<<dim3(128, BATCH), 256, 0, stream>>>(m1, m2);
  dilate_s2_k<32, 16><<<dim3(16, BATCH), 256, 0, stream>>>(m2, m3);
  dilate_s2_k<16, 8><<<dim3(2, BATCH), 256, 0, stream>>>(m3, m4);

  // padded-input prep: interior writes + border zeroing
  xmask_k<<<dim3(1024, BATCH), 256, 0, stream>>>(x, mask, xcp);
  zborder_k<66, 8><<<dim3((287496 + 255) / 256, BATCH), 256, 0, stream>>>((char*)xcp);
  zborder_k<66, 128><<<dim3((287496 + 255) / 256, BATCH), 256, 0, stream>>>((char*)h1p);
  zborder_k<34, 256><<<dim3((39304 + 255) / 256, BATCH), 256, 0, stream>>>((char*)h2p);

  // conv1 (reads xcp, writes h1p interior)
  conv1_mfma_k<128><<<dim3(262144 / 128, BATCH), 256, 0, stream>>>(xcp, wf1, b1, m1, h1p);

  // h3p border-zero AFTER conv1 (h3p aliases xcp)
  zborder_k<18, 512><<<dim3((5832 + 255) / 256, BATCH), 256, 0, stream>>>((char*)h3p);

  // conv blocks: 2-phase dbuf, occupancy-first tiles
  // conv2: BM64 BN128, 48KB LDS -> 3 blocks/CU, grid 512x1x4, A staged once
  conv_mfma2_k<64, 64, 128, 64, 32, 64, 128, 2, 2, 1, 1>
      <<<dim3(512, 1, BATCH), 256, 0, stream>>>(h1p, wf2, b2, m2, h2p);
  // conv3: ci-split 64, BM64 BN64, 32KB LDS -> 4 blocks/CU, grid 64x4x4
  conv_mfma2_k<64, 128, 256, 32, 16, 64, 64, 2, 2, 0, 1>
      <<<dim3(64, 4, BATCH), 256, 0, stream>>>(h2p, wf3, b3, m3, h3p);
  // conv4: ci-split 128, BM32 BN64, 2 waves, 48KB LDS, grid 16x8x4
  conv_mfma2_k<128, 256, 512, 16, 8, 32, 64, 1, 2, 0, 0>
      <<<dim3(16, 8, BATCH), 128, 0, stream>>>(h3p, wf4, b4, m4, h4);

  // pool + leaky relu
  pool_k<<<dim3(8, BATCH), 256, 0, stream>>>(h4, outp);
}